// Round 7
// baseline (248.486 us; speedup 1.0000x reference)
//
#include <hip/hip_runtime.h>
#include <hip/hip_fp16.h>
#include <math.h>

#define HID 32
#define NFEAT 100
#define CHUNK 4096   // edges per chunk in kc_sort
#define NCMAX 512    // max chunks (E/CHUNK = 391)
#define NBMAX 2048   // max buckets (N/64 = 1563)
#define CAP 2560     // LDS edge capacity per bucket (avg 1024, sigma 32 -> 48-sigma margin)

typedef _Float16 half2_v __attribute__((ext_vector_type(2)));

__device__ __forceinline__ float dot2h(unsigned int a, unsigned int b, float c) {
    return __builtin_amdgcn_fdot2(*(half2_v*)&a, *(half2_v*)&b, c, false);
}
__device__ __forceinline__ float2 h2f(unsigned int u) {
    return __half22float2(*(__half2*)&u);
}

// ---------------- K1: thread-per-node; X row in VGPRs, weights via scalar loads ----------
__global__ __launch_bounds__(256, 1) void k1_lin1_norm(
    const float* __restrict__ X, const float* __restrict__ w1,
    const float* __restrict__ b1,
    __half* __restrict__ xh, float* __restrict__ invn, int N)
{
    const int node = blockIdx.x * 256 + threadIdx.x;
    const int nc = node < N ? node : N - 1;
    const float4* Xr = (const float4*)(X + (size_t)nc * NFEAT);
    float4 xr[25];
    #pragma unroll
    for (int q = 0; q < 25; ++q) xr[q] = Xr[q];

    float d[HID];
    #pragma unroll
    for (int h = 0; h < HID; ++h) d[h] = 0.f;

    #pragma unroll
    for (int q = 0; q < 25; ++q) {
        #pragma unroll
        for (int h = 0; h < HID; ++h) {
            // w1[h*100 + 4q+j]: wave-uniform address -> scalar loads, scalar pipe
            d[h] = fmaf(xr[q].x, w1[h * NFEAT + q * 4 + 0], d[h]);
            d[h] = fmaf(xr[q].y, w1[h * NFEAT + q * 4 + 1], d[h]);
            d[h] = fmaf(xr[q].z, w1[h * NFEAT + q * 4 + 2], d[h]);
            d[h] = fmaf(xr[q].w, w1[h * NFEAT + q * 4 + 3], d[h]);
        }
    }
    float s = 0.f;
    #pragma unroll
    for (int h = 0; h < HID; ++h) {
        float v = fmaxf(d[h] + b1[h], 0.f);
        d[h] = v;
        s = fmaf(v, v, s);
    }
    float inv = 1.f / fmaxf(sqrtf(s), 1e-12f);

    if (node < N) {
        union { uint4 u[4]; __half2 h[16]; } pk;
        #pragma unroll
        for (int j = 0; j < 16; ++j) {
            __half2 t;
            t.x = __float2half_rn(d[2 * j]);
            t.y = __float2half_rn(d[2 * j + 1]);
            pk.h[j] = t;
        }
        uint4* dst = (uint4*)(xh + (size_t)node * HID);
        #pragma unroll
        for (int q = 0; q < 4; ++q) dst[q] = pk.u[q];
        invn[node] = inv;
    }
}

// ---------------- Chunk-local bucket sort; offsets written coalesced as u16 [c][NB+1] -------
__global__ __launch_bounds__(256) void kc_sort(
    const int* __restrict__ ei, int* __restrict__ binned,
    unsigned short* __restrict__ offU, int E, int NB, int NC)
{
    __shared__ int hist[NBMAX];
    __shared__ int off[NBMAX];
    const int tid = threadIdx.x;
    const int c = blockIdx.x;
    const int start = c * CHUNK;
    const int end = min(start + CHUNK, E);
    for (int b = tid; b < NB; b += 256) hist[b] = 0;
    __syncthreads();
    for (int e = start + tid; e < end; e += 256)
        atomicAdd(&hist[ei[E + e] >> 6], 1);
    __syncthreads();
    if (tid < 64) {   // wave 0: exclusive scan, 64 buckets/round with carry
        int carry = 0;
        for (int r = 0; r * 64 < NB; ++r) {
            int b = r * 64 + tid;
            int v = (b < NB) ? hist[b] : 0;
            int x = v;
            #pragma unroll
            for (int dd = 1; dd < 64; dd <<= 1) {
                int y = __shfl_up(x, dd, 64);
                if (tid >= dd) x += y;
            }
            if (b < NB) off[b] = carry + x - v;
            carry += __shfl(x, 63, 64);
        }
    }
    __syncthreads();
    const size_t urow = (size_t)c * (NB + 1);
    for (int b = tid; b < NB; b += 256) {
        offU[urow + b] = (unsigned short)off[b];   // coalesced u16 writes
        hist[b] = off[b];                           // reuse as local cursor
    }
    if (tid == 0) offU[urow + NB] = (unsigned short)(end - start);
    __syncthreads();
    for (int e = start + tid; e < end; e += 256) {
        int t = ei[E + e];
        int b = t >> 6;
        int pos = atomicAdd(&hist[b], 1);
        binned[start + pos] = ei[e] | ((t & 63) << 17);  // src<2^17, local 6 bits
    }
}

// ---------------- Transpose offU [C][R] u16 -> offT [R][C] (R=NB+1, C=NC) ----------------
__global__ __launch_bounds__(256) void k_transpose(
    const unsigned short* __restrict__ in, unsigned short* __restrict__ outp, int R, int C)
{
    __shared__ unsigned short tile[64][65];
    const int b0 = blockIdx.x * 64, c0 = blockIdx.y * 64;
    const int tx = threadIdx.x & 63, ty0 = threadIdx.x >> 6;
    for (int ty = ty0; ty < 64; ty += 4) {
        int c = c0 + ty, b = b0 + tx;
        tile[ty][tx] = (c < C && b < R) ? in[(size_t)c * R + b] : 0;
    }
    __syncthreads();
    for (int ty = ty0; ty < 64; ty += 4) {
        int b = b0 + ty, c = c0 + tx;
        if (b < R && c < C) outp[(size_t)b * C + c] = tile[tx][ty];
    }
}

// ---------------- Fused: single scattered pass -> LDS reorder -> fdot2 gather --------------
// Block = bucket (64 targets). Gather: 4 lanes per edge (uint4 = 8 halfs each), 16 slots.
__global__ __launch_bounds__(256) void k_fused(
    const int* __restrict__ binned, const unsigned short* __restrict__ offT,
    const __half* __restrict__ xh, const float* __restrict__ invn,
    const float* __restrict__ pbeta,
    const float* __restrict__ w2, const float* __restrict__ b2,
    float* __restrict__ out, int N, int NB, int NC)
{
    __shared__ unsigned short b0s[NCMAX], b1s[NCMAX];
    __shared__ int cnt[64], cur[64];
    __shared__ int led[CAP], led2[CAP];
    __shared__ int bcur_s;
    const int tid  = threadIdx.x;
    const int lane = tid & 63;
    const int wv   = tid >> 6;
    const int g4   = lane & 3;   // feature slice: halfs g4*8 .. g4*8+7 (uint4)
    const int slot = lane >> 2;  // edge slot 0..15
    const int b    = blockIdx.x;
    const float beta = *pbeta;
    float wA[8], wB[8];
    #pragma unroll
    for (int j = 0; j < 8; ++j) { wA[j] = w2[g4 * 8 + j]; wB[j] = w2[HID + g4 * 8 + j]; }
    const float bb0 = b2[0], bb1 = b2[1];

    for (int c = tid; c < NC; c += 256) {
        b0s[c] = offT[(size_t)b * NC + c];
        b1s[c] = offT[(size_t)(b + 1) * NC + c];
    }
    if (tid < 64) cnt[tid] = 0;
    if (tid == 0) bcur_s = 0;
    __syncthreads();

    // pass 1: append unordered into led[] + per-node counts (one cursor atomic per thread)
    {
        int total = 0;
        for (int c = tid; c < NC; c += 256) total += (int)b1s[c] - (int)b0s[c];
        int pos = total ? atomicAdd(&bcur_s, total) : 0;
        for (int c = tid; c < NC; c += 256) {
            const int gbase = c * CHUNK;
            const int j1 = b1s[c];
            for (int j = b0s[c]; j < j1; ++j) {
                int w = binned[gbase + j];
                atomicAdd(&cnt[w >> 17], 1);
                if (pos < CAP) led[pos] = w;
                ++pos;
            }
        }
    }
    __syncthreads();
    const int sz = bcur_s;
    if (tid < 64) {   // exclusive scan of 64 counts
        int v = cnt[tid], x = v;
        #pragma unroll
        for (int dd = 1; dd < 64; dd <<= 1) {
            int y = __shfl_up(x, dd, 64);
            if (tid >= dd) x += y;
        }
        cur[tid] = x - v;
    }
    __syncthreads();
    const bool fits = (sz <= CAP);
    if (fits) {   // LDS->LDS reorder: group by local node
        for (int i = tid; i < sz; i += 256) {
            int w = led[i];
            int pos = atomicAdd(&cur[w >> 17], 1);
            led2[pos] = w & 0x1FFFF;
        }
    }
    __syncthreads();

    for (int local = wv; local < 64; local += 4) {
        const int node = b * 64 + local;
        if (node >= N) break;   // monotone -> uniform break per wave

        const float ivt = invn[node];
        const uint4 ut = *(const uint4*)(xh + (size_t)node * HID + g4 * 8);
        float2 t0 = h2f(ut.x), t1 = h2f(ut.y), t2 = h2f(ut.z), t3 = h2f(ut.w);
        float sd = dot2h(ut.x, ut.x, dot2h(ut.y, ut.y, dot2h(ut.z, ut.z, dot2h(ut.w, ut.w, 0.f))));
        sd += __shfl_xor(sd, 1, 64); sd += __shfl_xor(sd, 2, 64);

        float a[8] = {0.f,0.f,0.f,0.f,0.f,0.f,0.f,0.f};
        float dsum = 0.f;
        const int deg = cnt[local];

        if (fits) {
            const int st = cur[local] - deg;   // cur ended at start+deg
            for (int e0 = 0; e0 < deg; e0 += 16) {
                const int e = e0 + slot;       // uniform within 4-lane group
                if (e < deg) {
                    const int s_ = led2[st + e];
                    const uint4 us = *(const uint4*)(xh + (size_t)s_ * HID + g4 * 8);
                    float p = dot2h(ut.x, us.x, dot2h(ut.y, us.y,
                              dot2h(ut.z, us.z, dot2h(ut.w, us.w, 0.f))));
                    p += __shfl_xor(p, 1, 64); p += __shfl_xor(p, 2, 64);
                    const float ivs = invn[s_];
                    const float wgt = __expf(beta * p * ivt * ivs);   // cos in [-1,1]: safe
                    float2 f0 = h2f(us.x), f1 = h2f(us.y), f2 = h2f(us.z), f3 = h2f(us.w);
                    a[0] = fmaf(wgt, f0.x, a[0]); a[1] = fmaf(wgt, f0.y, a[1]);
                    a[2] = fmaf(wgt, f1.x, a[2]); a[3] = fmaf(wgt, f1.y, a[3]);
                    a[4] = fmaf(wgt, f2.x, a[4]); a[5] = fmaf(wgt, f2.y, a[5]);
                    a[6] = fmaf(wgt, f3.x, a[6]); a[7] = fmaf(wgt, f3.y, a[7]);
                    dsum += wgt;
                }
            }
        } else {
            // fallback (bucket > CAP, practically never): filter all sub-runs from global
            for (int c = 0; c < NC; ++c) {
                const int gbase = c * CHUNK;
                const int j1 = b1s[c];
                for (int j = (int)b0s[c] + slot; j < j1; j += 16) {
                    const int wrd = binned[gbase + j];
                    const bool ok = ((wrd >> 17) == local);
                    const int s_ = ok ? (wrd & 0x1FFFF) : 0;
                    const uint4 us = *(const uint4*)(xh + (size_t)s_ * HID + g4 * 8);
                    float p = dot2h(ut.x, us.x, dot2h(ut.y, us.y,
                              dot2h(ut.z, us.z, dot2h(ut.w, us.w, 0.f))));
                    p += __shfl_xor(p, 1, 64); p += __shfl_xor(p, 2, 64);
                    const float ivs = invn[s_];
                    const float wgt = ok ? __expf(beta * p * ivt * ivs) : 0.f;
                    float2 f0 = h2f(us.x), f1 = h2f(us.y), f2 = h2f(us.z), f3 = h2f(us.w);
                    a[0] = fmaf(wgt, f0.x, a[0]); a[1] = fmaf(wgt, f0.y, a[1]);
                    a[2] = fmaf(wgt, f1.x, a[2]); a[3] = fmaf(wgt, f1.y, a[3]);
                    a[4] = fmaf(wgt, f2.x, a[4]); a[5] = fmaf(wgt, f2.y, a[5]);
                    a[6] = fmaf(wgt, f3.x, a[6]); a[7] = fmaf(wgt, f3.y, a[7]);
                    dsum += wgt;
                }
            }
        }
        // combine the 16 edge slots
        #pragma unroll
        for (int m = 4; m <= 32; m <<= 1) {
            #pragma unroll
            for (int j = 0; j < 8; ++j) a[j] += __shfl_xor(a[j], m, 64);
            dsum += __shfl_xor(dsum, m, 64);
        }
        // self-loop
        const float wself = __expf(beta * sd * ivt * ivt);
        a[0] = fmaf(wself, t0.x, a[0]); a[1] = fmaf(wself, t0.y, a[1]);
        a[2] = fmaf(wself, t1.x, a[2]); a[3] = fmaf(wself, t1.y, a[3]);
        a[4] = fmaf(wself, t2.x, a[4]); a[5] = fmaf(wself, t2.y, a[5]);
        a[6] = fmaf(wself, t3.x, a[6]); a[7] = fmaf(wself, t3.y, a[7]);
        dsum += wself;

        const float invd = 1.f / dsum;
        float l0 = 0.f, l1 = 0.f;
        #pragma unroll
        for (int j = 0; j < 8; ++j) {
            float o = a[j] * invd;
            l0 = fmaf(o, wA[j], l0);
            l1 = fmaf(o, wB[j], l1);
        }
        l0 += __shfl_xor(l0, 1, 64); l0 += __shfl_xor(l0, 2, 64);
        l1 += __shfl_xor(l1, 1, 64); l1 += __shfl_xor(l1, 2, 64);
        if (lane == 0) {
            l0 += bb0; l1 += bb1;
            float m = fmaxf(l0, l1);
            float lse = m + __logf(__expf(l0 - m) + __expf(l1 - m));
            out[2 * (size_t)node]     = l0 - lse;
            out[2 * (size_t)node + 1] = l1 - lse;
        }
    }
}

extern "C" void kernel_launch(void* const* d_in, const int* in_sizes, int n_in,
                              void* d_out, int out_size, void* d_ws, size_t ws_size,
                              hipStream_t stream) {
    const float* X    = (const float*)d_in[0];
    const float* w1   = (const float*)d_in[1];
    const float* b1   = (const float*)d_in[2];
    const float* beta = (const float*)d_in[3];
    const float* w2   = (const float*)d_in[4];
    const float* b2   = (const float*)d_in[5];
    const int*   ei   = (const int*)d_in[6];

    const int N = in_sizes[0] / NFEAT;       // 100000
    const int E = in_sizes[6] / 2;           // 1600000
    const int NB = (N + 63) >> 6;            // 1563 target buckets
    const int NC = (E + CHUNK - 1) / CHUNK;  // 391 chunks
    const int R  = NB + 1;                   // offset-table rows

    char* wsb = (char*)d_ws;
    __half* xhp  = (__half*)wsb;          wsb += (size_t)N * HID * 2;   // 6.4 MB
    float* invn  = (float*)wsb;           wsb += (size_t)N * 4;
    int*   binned = (int*)wsb;            wsb += (size_t)E * 4;         // 6.4 MB
    unsigned short* offU = (unsigned short*)wsb; wsb += (size_t)R * NC * 2;
    unsigned short* offT = (unsigned short*)wsb; wsb += (size_t)R * NC * 2;
    float* out   = (float*)d_out;

    k1_lin1_norm<<<(N + 255) / 256, 256, 0, stream>>>(X, w1, b1, xhp, invn, N);
    kc_sort<<<NC, 256, 0, stream>>>(ei, binned, offU, E, NB, NC);
    k_transpose<<<dim3((R + 63) / 64, (NC + 63) / 64), 256, 0, stream>>>(offU, offT, R, NC);
    k_fused<<<NB, 256, 0, stream>>>(binned, offT, xhp, invn, beta, w2, b2, out, N, NB, NC);
}